// Round 2
// baseline (388.070 us; speedup 1.0000x reference)
//
#include <hip/hip_runtime.h>
#include <stdint.h>
#include <string.h>

// BoltzmannGateSTE: out = x * (|x| >= T), T = k-th largest |x|, k = int(n/e).
// Fast path (1 full read + 1 full write):
//   partition pass with compile-time bracket [lo,hi) = [0.88,0.92) magnitudes:
//     u >= hi  -> keep (write x), count c_hi
//     u <  lo  -> zero
//     else     -> candidate: placeholder 0 + append (bits,idx) to per-block buffer
//                 + 4096-bin LDS histogram of candidate bits[30:19]
//   then exact radix select runs over the ~710K candidates (5.7 MB), verified
//   on-device: c_hi < k <= c_hi + #cand. If verification fails (or candidate
//   overflow), a gated fallback chain (the proven round-1 3-pass radix select)
//   produces the exact answer for arbitrary inputs.
// All selection logic device-side (graph capture forbids host readback).

#define SEL_T 1024

constexpr int H_BLOCKS  = 512;
constexpr int H_THREADS = 1024;
constexpr int NBIN1     = 4096;      // bits [30:19]
constexpr int NFINE     = 1 << 19;   // bits [18:0]
constexpr int NCOARSE   = 512;       // fine >> 10
constexpr int CAP       = 8192;      // candidate capacity per partition block

// state slots
#define S_PREF 0
#define S_K1   1
#define S_T    2
#define S_FLAG 3   // nonzero -> fallback chain active
#define S_CHI  4

// gate: 0 = always run, 1 = run iff FLAG!=0, 2 = run iff FLAG==0
__device__ __forceinline__ bool gate_skip(const unsigned* state, int gate) {
    if (gate == 0) return false;
    unsigned fl = state[S_FLAG];
    return (gate == 1) ? (fl == 0u) : (fl != 0u);
}

// ---------------- fast path: partition + candidate extraction ----------------
__global__ __launch_bounds__(H_THREADS)
void pass_partition(const uint4* __restrict__ x, long long n4,
                    unsigned lo, unsigned hi,
                    uint4* __restrict__ out, uint2* __restrict__ cand,
                    unsigned* __restrict__ bcnt, unsigned* __restrict__ chist,
                    unsigned* __restrict__ state, int cap)
{
    __shared__ unsigned h12[NBIN1];
    __shared__ unsigned s_cnt;
    for (int i = threadIdx.x; i < NBIN1; i += H_THREADS) h12[i] = 0u;
    if (threadIdx.x == 0) s_cnt = 0u;
    __syncthreads();

    uint2* mycand = cand + (size_t)blockIdx.x * cap;
    unsigned chi = 0;
    long long stride = (long long)gridDim.x * H_THREADS;
    for (long long i = (long long)blockIdx.x * H_THREADS + threadIdx.x; i < n4; i += stride) {
        uint4 v = x[i];
        uint4 r;
        unsigned idx0 = (unsigned)((unsigned long long)i << 2);
#define DO_COMP(c, off)                                                          \
        { unsigned u = v.c & 0x7FFFFFFFu;                                        \
          bool kp = (u >= hi);                                                   \
          chi += kp ? 1u : 0u;                                                   \
          r.c = kp ? v.c : 0u;                                                   \
          if (u >= lo && !kp) {                                                  \
              atomicAdd(&h12[u >> 19], 1u);                                      \
              unsigned s = atomicAdd(&s_cnt, 1u);                                \
              if ((int)s < cap) mycand[s] = make_uint2(v.c, idx0 + off);         \
          } }
        DO_COMP(x, 0) DO_COMP(y, 1) DO_COMP(z, 2) DO_COMP(w, 3)
#undef DO_COMP
        out[i] = r;
    }

    // wave-reduce c_hi, one global atomic per wave
    for (int m = 32; m; m >>= 1) chi += __shfl_xor(chi, m, 64);
    __syncthreads();   // h12, s_cnt complete
    for (int i = threadIdx.x; i < NBIN1; i += H_THREADS)
        if (h12[i]) atomicAdd(&chist[i], h12[i]);
    if ((threadIdx.x & 63) == 0) atomicAdd(&state[S_CHI], chi);
    if (threadIdx.x == 0) {
        bcnt[blockIdx.x] = s_cnt;
        if ((int)s_cnt > cap) atomicOr(&state[S_FLAG], 1u);
    }
}

// ---------------- descending block select over a histogram ----------------
// Finds bin b with sum_{j>b} hist[j] < k <= sum_{j>=b} hist[j].
// s_res[0]=b (or -1 if total<k), s_res[1]=remaining rank in bin b.
__device__ void select_desc(const unsigned* __restrict__ hist, int nbins,
                            unsigned k, unsigned* s_scan, int* s_res)
{
    int tid = threadIdx.x;
    if (tid == 0) { s_res[0] = -1; s_res[1] = 0; }
    __syncthreads();
    unsigned running = 0;
    for (int top = nbins; top > 0; top -= SEL_T) {
        int bin = top - 1 - tid;
        unsigned v = (bin >= 0) ? hist[bin] : 0u;
        s_scan[tid] = v;
        __syncthreads();
        for (int off = 1; off < SEL_T; off <<= 1) {
            unsigned add = (tid >= off) ? s_scan[tid - off] : 0u;
            __syncthreads();
            s_scan[tid] += add;
            __syncthreads();
        }
        unsigned p     = s_scan[tid];
        unsigned pprev = (tid > 0) ? s_scan[tid - 1] : 0u;
        unsigned total = s_scan[SEL_T - 1];
        __syncthreads();
        if (running + total >= k) {
            if (bin >= 0 && running + p >= k && running + pprev < k) {
                s_res[0] = bin;
                s_res[1] = (int)(k - running - pprev);
            }
            __syncthreads();
            return;
        }
        running += total;
    }
    __syncthreads();   // s_res[0] stays -1: total < k
}

// fast-path coarse select over candidate histogram; verifies the bracket
__global__ __launch_bounds__(SEL_T)
void cand_select12(const unsigned* __restrict__ chist, unsigned* __restrict__ state,
                   unsigned k)
{
    if (state[S_FLAG]) return;                 // overflow in pass_partition
    __shared__ unsigned s_scan[SEL_T];
    __shared__ int s_res[2];
    unsigned chi = state[S_CHI];
    if (chi >= k) { if (threadIdx.x == 0) state[S_FLAG] = 1u; return; }
    select_desc(chist, NBIN1, k - chi, s_scan, s_res);
    if (threadIdx.x == 0) {
        if (s_res[0] < 0) state[S_FLAG] = 1u;  // not enough candidates: T < lo
        else { state[S_PREF] = (unsigned)s_res[0]; state[S_K1] = (unsigned)s_res[1]; }
    }
}

__global__ __launch_bounds__(256)
void cand_hist_fine(const uint2* __restrict__ cand, const unsigned* __restrict__ bcnt,
                    const unsigned* __restrict__ state,
                    unsigned* __restrict__ fineB, unsigned* __restrict__ coarseB, int cap)
{
    if (state[S_FLAG]) return;
    __shared__ unsigned hc[NCOARSE];
    for (int i = threadIdx.x; i < NCOARSE; i += 256) hc[i] = 0u;
    __syncthreads();
    unsigned pref = state[S_PREF];
    unsigned cnt  = bcnt[blockIdx.x];
    if (cnt > (unsigned)cap) cnt = (unsigned)cap;
    const uint2* my = cand + (size_t)blockIdx.x * cap;
    for (unsigned j = threadIdx.x; j < cnt; j += 256) {
        unsigned u = my[j].x & 0x7FFFFFFFu;
        if ((u >> 19) == pref) {
            unsigned f = u & (NFINE - 1);
            atomicAdd(&fineB[f], 1u);
            atomicAdd(&hc[f >> 10], 1u);
        }
    }
    __syncthreads();
    for (int i = threadIdx.x; i < NCOARSE; i += 256)
        if (hc[i]) atomicAdd(&coarseB[i], hc[i]);
}

__global__ __launch_bounds__(SEL_T)
void select2_kernel(const unsigned* __restrict__ fineB, const unsigned* __restrict__ coarseB,
                    unsigned* __restrict__ state, int gate)
{
    if (gate_skip(state, gate)) return;
    __shared__ unsigned s_scan[SEL_T];
    __shared__ int s_res[2];
    unsigned pref = state[S_PREF];
    unsigned k    = state[S_K1];
    select_desc(coarseB, NCOARSE, k, s_scan, s_res);
    int c       = (s_res[0] < 0) ? 0 : s_res[0];
    unsigned k1 = (s_res[0] < 0) ? 1u : (unsigned)s_res[1];
    __syncthreads();
    select_desc(fineB + (size_t)c * 1024, 1024, k1, s_scan, s_res);
    int f = (s_res[0] < 0) ? 0 : s_res[0];
    if (threadIdx.x == 0)
        state[S_T] = (pref << 19) | ((unsigned)c << 10) | (unsigned)f;
}

__global__ __launch_bounds__(256)
void cand_fixup(const uint2* __restrict__ cand, const unsigned* __restrict__ bcnt,
                const unsigned* __restrict__ state, float* __restrict__ out, int cap)
{
    if (state[S_FLAG]) return;
    unsigned T   = state[S_T];
    unsigned cnt = bcnt[blockIdx.x];
    if (cnt > (unsigned)cap) cnt = (unsigned)cap;
    const uint2* my = cand + (size_t)blockIdx.x * cap;
    for (unsigned j = threadIdx.x; j < cnt; j += 256) {
        uint2 e = my[j];
        if ((e.x & 0x7FFFFFFFu) >= T) out[e.y] = __uint_as_float(e.x);
    }
}

// ---------------- fallback chain (round-1 proven pipeline, gated) ----------------
__global__ __launch_bounds__(H_THREADS)
void hist_pass1(const uint4* __restrict__ x, long long n4, unsigned* __restrict__ hists,
                const unsigned* __restrict__ state, int gate)
{
    if (gate_skip(state, gate)) return;
    __shared__ unsigned h[NBIN1];
    for (int i = threadIdx.x; i < NBIN1; i += H_THREADS) h[i] = 0u;
    __syncthreads();
    long long stride = (long long)gridDim.x * H_THREADS;
    for (long long i = (long long)blockIdx.x * H_THREADS + threadIdx.x; i < n4; i += stride) {
        uint4 v = x[i];
        atomicAdd(&h[(v.x & 0x7FFFFFFFu) >> 19], 1u);
        atomicAdd(&h[(v.y & 0x7FFFFFFFu) >> 19], 1u);
        atomicAdd(&h[(v.z & 0x7FFFFFFFu) >> 19], 1u);
        atomicAdd(&h[(v.w & 0x7FFFFFFFu) >> 19], 1u);
    }
    __syncthreads();
    unsigned* o = hists + (size_t)blockIdx.x * NBIN1;
    for (int i = threadIdx.x; i < NBIN1; i += H_THREADS) o[i] = h[i];
}

__global__ void hist_reduce(const unsigned* __restrict__ hists, unsigned* __restrict__ histA,
                            int nblocks, const unsigned* __restrict__ state, int gate)
{
    if (gate_skip(state, gate)) return;
    int bin = blockIdx.x * blockDim.x + threadIdx.x;
    if (bin >= NBIN1) return;
    unsigned s = 0;
    for (int b = 0; b < nblocks; ++b) s += hists[(size_t)b * NBIN1 + bin];
    histA[bin] = s;
}

__global__ __launch_bounds__(SEL_T)
void select1_kernel(const unsigned* __restrict__ histA, unsigned* __restrict__ state,
                    unsigned k, int gate)
{
    if (gate_skip(state, gate)) return;
    __shared__ unsigned s_scan[SEL_T];
    __shared__ int s_res[2];
    select_desc(histA, NBIN1, k, s_scan, s_res);
    if (threadIdx.x == 0) {
        state[S_PREF] = (s_res[0] < 0) ? 0u : (unsigned)s_res[0];
        state[S_K1]   = (s_res[0] < 0) ? 1u : (unsigned)s_res[1];
    }
}

__global__ __launch_bounds__(H_THREADS)
void hist_pass2(const uint4* __restrict__ x, long long n4, const unsigned* __restrict__ state,
                unsigned* __restrict__ fineB, unsigned* __restrict__ coarseB, int gate)
{
    if (gate_skip(state, gate)) return;
    __shared__ unsigned hc[NCOARSE];
    for (int i = threadIdx.x; i < NCOARSE; i += H_THREADS) hc[i] = 0u;
    __syncthreads();
    unsigned pref = state[S_PREF];
    long long stride = (long long)gridDim.x * H_THREADS;
    for (long long i = (long long)blockIdx.x * H_THREADS + threadIdx.x; i < n4; i += stride) {
        uint4 v = x[i];
        unsigned u;
#define DO_C(c) u = v.c & 0x7FFFFFFFu;                                           \
        if ((u >> 19) == pref) {                                                 \
            atomicAdd(&fineB[u & (NFINE - 1)], 1u);                              \
            atomicAdd(&hc[(u & (NFINE - 1)) >> 10], 1u); }
        DO_C(x) DO_C(y) DO_C(z) DO_C(w)
#undef DO_C
    }
    __syncthreads();
    for (int i = threadIdx.x; i < NCOARSE; i += H_THREADS)
        if (hc[i]) atomicAdd(&coarseB[i], hc[i]);
}

__global__ __launch_bounds__(256)
void mask_kernel(const uint4* __restrict__ x, uint4* __restrict__ out, long long n4,
                 const unsigned* __restrict__ state, int gate)
{
    if (gate_skip(state, gate)) return;
    unsigned t = state[S_T];
    long long stride = (long long)gridDim.x * 256;
    for (long long i = (long long)blockIdx.x * 256 + threadIdx.x; i < n4; i += stride) {
        uint4 v = x[i];
        uint4 r;
        r.x = ((v.x & 0x7FFFFFFFu) >= t) ? v.x : 0u;
        r.y = ((v.y & 0x7FFFFFFFu) >= t) ? v.y : 0u;
        r.z = ((v.z & 0x7FFFFFFFu) >= t) ? v.z : 0u;
        r.w = ((v.w & 0x7FFFFFFFu) >= t) ? v.w : 0u;
        out[i] = r;
    }
}

// ---------------- host ----------------
extern "C" void kernel_launch(void* const* d_in, const int* in_sizes, int n_in,
                              void* d_out, int out_size, void* d_ws, size_t ws_size,
                              hipStream_t stream)
{
    long long n = (long long)in_sizes[0];
    if (n <= 0) return;
    long long n4 = n >> 2;   // n = 4*4096*2048, divisible by 4

    const double FRACTION = 1.0 / 2.718281828459045;   // matches Python 1.0/math.e
    long long k = (long long)((double)n * FRACTION);
    if (k < 1) k = 1;

    // bracket [0.88, 0.92): P(|x|>=0.92)=0.3576n < k=0.3679n <= P(|x|>=0.88)=0.3788n
    // margins ~±350K elements ≈ 120σ for iid N(0,1); exact on-device verification
    // + fallback covers everything else.
    unsigned lo, hi;
    { float f = 0.88f; memcpy(&lo, &f, 4); lo &= 0x7FFFFFFFu; }
    { float f = 0.92f; memcpy(&hi, &f, 4); hi &= 0x7FFFFFFFu; }

    // buffer layout (relative to bb)
    const size_t off_histA  = 0;
    const size_t off_chist  = off_histA  + (size_t)NBIN1 * 4;
    const size_t off_fineB  = off_chist  + (size_t)NBIN1 * 4;
    const size_t off_coarse = off_fineB  + (size_t)NFINE * 4;
    const size_t off_bcnt   = off_coarse + (size_t)NCOARSE * 4;    // zero up to here
    const size_t off_hists  = off_bcnt   + (size_t)H_BLOCKS * 4;
    const size_t off_cand   = off_hists  + (size_t)H_BLOCKS * NBIN1 * 4;
    const size_t cand_bytes = (size_t)H_BLOCKS * CAP * 8;
    const size_t need_fast  = 64 + off_cand + cand_bytes;
    const size_t need_ws    = 64 + off_cand;

    unsigned* state = (unsigned*)d_ws;
    uint8_t*  bb;
    bool fast;
    if (ws_size >= need_fast)      { bb = (uint8_t*)d_ws + 64; fast = true;  }
    else if (ws_size >= need_ws)   { bb = (uint8_t*)d_ws + 64; fast = false; }
    else                           { bb = (uint8_t*)d_out;     fast = false; } // staged in d_out

    unsigned* histA   = (unsigned*)(bb + off_histA);
    unsigned* chist   = (unsigned*)(bb + off_chist);
    unsigned* fineB   = (unsigned*)(bb + off_fineB);
    unsigned* coarseB = (unsigned*)(bb + off_coarse);
    unsigned* bcnt    = (unsigned*)(bb + off_bcnt);
    unsigned* hists   = (unsigned*)(bb + off_hists);
    uint2*    cand    = (uint2*)   (bb + off_cand);

    // ws/out are re-poisoned to 0xAA before every timed launch — zero our accumulators
    hipMemsetAsync(bb, 0, off_bcnt, stream);
    hipMemsetAsync(state, 0, 64, stream);

    const uint4* x = (const uint4*)d_in[0];

    if (fast) {
        pass_partition<<<H_BLOCKS, H_THREADS, 0, stream>>>(x, n4, lo, hi, (uint4*)d_out,
                                                           cand, bcnt, chist, state, CAP);
        cand_select12 <<<1, SEL_T, 0, stream>>>(chist, state, (unsigned)k);
        cand_hist_fine<<<H_BLOCKS, 256, 0, stream>>>(cand, bcnt, state, fineB, coarseB, CAP);
        select2_kernel<<<1, SEL_T, 0, stream>>>(fineB, coarseB, state, 2);
        cand_fixup    <<<H_BLOCKS, 256, 0, stream>>>(cand, bcnt, state, (float*)d_out, CAP);
        // gated fallback chain — no-ops unless verification failed
        hist_pass1    <<<H_BLOCKS, H_THREADS, 0, stream>>>(x, n4, hists, state, 1);
        hist_reduce   <<<(NBIN1 + 255) / 256, 256, 0, stream>>>(hists, histA, H_BLOCKS, state, 1);
        select1_kernel<<<1, SEL_T, 0, stream>>>(histA, state, (unsigned)k, 1);
        hist_pass2    <<<H_BLOCKS, H_THREADS, 0, stream>>>(x, n4, state, fineB, coarseB, 1);
        select2_kernel<<<1, SEL_T, 0, stream>>>(fineB, coarseB, state, 1);
        mask_kernel   <<<2048, 256, 0, stream>>>(x, (uint4*)d_out, n4, state, 1);
    } else {
        hist_pass1    <<<H_BLOCKS, H_THREADS, 0, stream>>>(x, n4, hists, state, 0);
        hist_reduce   <<<(NBIN1 + 255) / 256, 256, 0, stream>>>(hists, histA, H_BLOCKS, state, 0);
        select1_kernel<<<1, SEL_T, 0, stream>>>(histA, state, (unsigned)k, 0);
        hist_pass2    <<<H_BLOCKS, H_THREADS, 0, stream>>>(x, n4, state, fineB, coarseB, 0);
        select2_kernel<<<1, SEL_T, 0, stream>>>(fineB, coarseB, state, 0);
        mask_kernel   <<<2048, 256, 0, stream>>>(x, (uint4*)d_out, n4, state, 0);
    }
}

// Round 3
// 362.459 us; speedup vs baseline: 1.0707x; 1.0707x over previous
//
#include <hip/hip_runtime.h>
#include <stdint.h>
#include <string.h>

// BoltzmannGateSTE: out = x * (|x| >= T), T = k-th largest |x|, k = int(n/e).
// Fast path = ONE full read + ONE full write:
//   pass_partition: stream x -> out with bracket [lo,hi) = [0.88,0.92):
//     u >= hi -> keep, count chi;  u < lo -> zero;
//     else candidate -> placeholder 0 + ballot-compacted append (bits,idx) to a
//     per-WAVE buffer (no atomics, no LDS in the hot loop), count cmi (u>=mid).
//   The bracket spans exactly TWO coarse bins (2028/2029), so coarse select
//   reduces to comparing (k-chi) against cmi. Fine 19-bit radix select runs on
//   the ~720K candidates only. Exact on-device verification (chi < k <= chi+tot,
//   no buffer overflow) gates a fallback chain (proven round-1 3-pass radix
//   select) that is exact for arbitrary inputs.

#define SEL_T 1024

constexpr int H_BLOCKS  = 512;    // fallback chain geometry
constexpr int H_THREADS = 1024;
constexpr int NBIN1     = 4096;   // bits [30:19]
constexpr int NFINE     = 1 << 19;
constexpr int NCOARSE   = 512;    // fine >> 10

constexpr int P_GRID = 4096;      // partition pass geometry
constexpr int P_BLK  = 256;
constexpr int P_WPB  = P_BLK / 64;           // 4 waves/block
constexpr int NWAVES = P_GRID * P_WPB;       // 16384
constexpr int CAPW   = 128;                  // slots per wave (lambda ~43)

// state slots
#define S_PREF 0
#define S_K1   1
#define S_T    2
#define S_FLAG 3   // nonzero -> fallback chain active

// gate: 0 = always run, 1 = run iff FLAG!=0, 2 = run iff FLAG==0
__device__ __forceinline__ bool gate_skip(const unsigned* state, int gate) {
    if (gate == 0) return false;
    unsigned fl = state[S_FLAG];
    return (gate == 1) ? (fl == 0u) : (fl != 0u);
}

// ---------------- fast path: atomic-free partition + wave compaction ----------------
__global__ __launch_bounds__(P_BLK, 8)
void pass_partition(const uint4* __restrict__ x, long long n4,
                    unsigned lo, unsigned hi, unsigned mid,
                    uint4* __restrict__ out, uint2* __restrict__ cand,
                    unsigned* __restrict__ wavecnt,
                    unsigned* __restrict__ blkchi, unsigned* __restrict__ blkmid,
                    unsigned* __restrict__ state)
{
    typedef unsigned uv4 __attribute__((ext_vector_type(4)));
    const int lane  = threadIdx.x & 63;
    const int wid   = threadIdx.x >> 6;
    const int gwave = blockIdx.x * P_WPB + wid;
    uint2* my = cand + (size_t)gwave * CAPW;
    const unsigned long long lt = (1ull << lane) - 1ull;

    unsigned wcnt = 0;               // wave-uniform candidate count
    unsigned chi = 0, cmi = 0;       // per-thread tallies
    const long long stride = (long long)gridDim.x * P_BLK;
#pragma unroll 2
    for (long long i = (long long)blockIdx.x * P_BLK + threadIdx.x; i < n4; i += stride) {
        uint4 v = x[i];
        uint4 r;
        unsigned idx0 = (unsigned)(i << 2);
#define DO_COMP(c, off)                                                        \
        { unsigned b = v.c, u = b & 0x7FFFFFFFu;                               \
          bool kp = (u >= hi);                                                 \
          bool cd = (u >= lo) & !kp;                                           \
          chi += (unsigned)kp;                                                 \
          cmi += (unsigned)(cd & (u >= mid));                                  \
          r.c = kp ? b : 0u;                                                   \
          unsigned long long m = __ballot(cd);                                 \
          if (cd) {                                                            \
              unsigned pos = wcnt + (unsigned)__popcll(m & lt);                \
              if (pos < (unsigned)CAPW) my[pos] = make_uint2(b, idx0 + off);   \
          }                                                                    \
          wcnt += (unsigned)__popcll(m); }
        DO_COMP(x, 0) DO_COMP(y, 1) DO_COMP(z, 2) DO_COMP(w, 3)
#undef DO_COMP
        __builtin_nontemporal_store(*(uv4*)&r, (uv4*)(out + i));
    }

    // wave-reduce chi/cmi (no atomics anywhere)
    for (int m = 32; m; m >>= 1) {
        chi += __shfl_xor(chi, m, 64);
        cmi += __shfl_xor(cmi, m, 64);
    }
    __shared__ unsigned s_chi[P_WPB], s_mid[P_WPB];
    if (lane == 0) {
        s_chi[wid] = chi;
        s_mid[wid] = cmi;
        wavecnt[gwave] = (wcnt < (unsigned)CAPW) ? wcnt : (unsigned)CAPW;
        if (wcnt > (unsigned)CAPW) atomicOr(&state[S_FLAG], 1u);
    }
    __syncthreads();
    if (threadIdx.x == 0) {
        unsigned a = 0, b = 0;
        for (int w = 0; w < P_WPB; ++w) { a += s_chi[w]; b += s_mid[w]; }
        blkchi[blockIdx.x] = a;
        blkmid[blockIdx.x] = b;
    }
}

// 1-block: sum tallies, verify bracket, pick coarse bin (binhi or binhi-1)
__global__ __launch_bounds__(256)
void fast_select(const unsigned* __restrict__ blkchi, const unsigned* __restrict__ blkmid,
                 const unsigned* __restrict__ wavecnt, unsigned* __restrict__ state,
                 unsigned k, unsigned binhi)
{
    if (state[S_FLAG]) return;       // candidate overflow in pass_partition
    __shared__ unsigned long long s[3][4];
    unsigned long long chi = 0, mid = 0, tot = 0;
    for (int i = threadIdx.x; i < P_GRID; i += 256) { chi += blkchi[i]; mid += blkmid[i]; }
    for (int i = threadIdx.x; i < NWAVES; i += 256) tot += wavecnt[i];
    for (int m = 32; m; m >>= 1) {
        chi += __shfl_xor(chi, m, 64);
        mid += __shfl_xor(mid, m, 64);
        tot += __shfl_xor(tot, m, 64);
    }
    int wid = threadIdx.x >> 6, lane = threadIdx.x & 63;
    if (lane == 0) { s[0][wid] = chi; s[1][wid] = mid; s[2][wid] = tot; }
    __syncthreads();
    if (threadIdx.x == 0) {
        chi = s[0][0] + s[0][1] + s[0][2] + s[0][3];
        mid = s[1][0] + s[1][1] + s[1][2] + s[1][3];
        tot = s[2][0] + s[2][1] + s[2][2] + s[2][3];
        if (chi >= (unsigned long long)k || chi + tot < (unsigned long long)k) {
            state[S_FLAG] = 1u;      // T outside [lo,hi): exact fallback
        } else {
            unsigned kp = (unsigned)((unsigned long long)k - chi);
            if (mid >= (unsigned long long)kp) { state[S_PREF] = binhi;     state[S_K1] = kp; }
            else { state[S_PREF] = binhi - 1; state[S_K1] = kp - (unsigned)mid; }
        }
    }
}

__global__ __launch_bounds__(256)
void cand_hist_fine(const uint2* __restrict__ cand, const unsigned* __restrict__ wavecnt,
                    const unsigned* __restrict__ state,
                    unsigned* __restrict__ fineB, unsigned* __restrict__ coarseB)
{
    if (state[S_FLAG]) return;
    __shared__ unsigned hc[NCOARSE];
    for (int i = threadIdx.x; i < NCOARSE; i += 256) hc[i] = 0u;
    __syncthreads();
    unsigned pref = state[S_PREF];
    for (int r = blockIdx.x; r < NWAVES; r += gridDim.x) {
        unsigned cnt = wavecnt[r];
        const uint2* my = cand + (size_t)r * CAPW;
        for (unsigned j = threadIdx.x; j < cnt; j += 256) {
            unsigned u = my[j].x & 0x7FFFFFFFu;
            if ((u >> 19) == pref) {
                unsigned f = u & (NFINE - 1);
                atomicAdd(&fineB[f], 1u);
                atomicAdd(&hc[f >> 10], 1u);
            }
        }
    }
    __syncthreads();
    for (int i = threadIdx.x; i < NCOARSE; i += 256)
        if (hc[i]) atomicAdd(&coarseB[i], hc[i]);
}

// ---------------- descending block select over a histogram ----------------
__device__ void select_desc(const unsigned* __restrict__ hist, int nbins,
                            unsigned k, unsigned* s_scan, int* s_res)
{
    int tid = threadIdx.x;
    if (tid == 0) { s_res[0] = -1; s_res[1] = 0; }
    __syncthreads();
    unsigned running = 0;
    for (int top = nbins; top > 0; top -= SEL_T) {
        int bin = top - 1 - tid;
        unsigned v = (bin >= 0) ? hist[bin] : 0u;
        s_scan[tid] = v;
        __syncthreads();
        for (int off = 1; off < SEL_T; off <<= 1) {
            unsigned add = (tid >= off) ? s_scan[tid - off] : 0u;
            __syncthreads();
            s_scan[tid] += add;
            __syncthreads();
        }
        unsigned p     = s_scan[tid];
        unsigned pprev = (tid > 0) ? s_scan[tid - 1] : 0u;
        unsigned total = s_scan[SEL_T - 1];
        __syncthreads();
        if (running + total >= k) {
            if (bin >= 0 && running + p >= k && running + pprev < k) {
                s_res[0] = bin;
                s_res[1] = (int)(k - running - pprev);
            }
            __syncthreads();
            return;
        }
        running += total;
    }
    __syncthreads();
}

__global__ __launch_bounds__(SEL_T)
void select2_kernel(const unsigned* __restrict__ fineB, const unsigned* __restrict__ coarseB,
                    unsigned* __restrict__ state, int gate)
{
    if (gate_skip(state, gate)) return;
    __shared__ unsigned s_scan[SEL_T];
    __shared__ int s_res[2];
    unsigned pref = state[S_PREF];
    unsigned k    = state[S_K1];
    select_desc(coarseB, NCOARSE, k, s_scan, s_res);
    int c       = (s_res[0] < 0) ? 0 : s_res[0];
    unsigned k1 = (s_res[0] < 0) ? 1u : (unsigned)s_res[1];
    __syncthreads();
    select_desc(fineB + (size_t)c * 1024, 1024, k1, s_scan, s_res);
    int f = (s_res[0] < 0) ? 0 : s_res[0];
    if (threadIdx.x == 0)
        state[S_T] = (pref << 19) | ((unsigned)c << 10) | (unsigned)f;
}

__global__ __launch_bounds__(256)
void cand_fixup(const uint2* __restrict__ cand, const unsigned* __restrict__ wavecnt,
                const unsigned* __restrict__ state, float* __restrict__ out)
{
    if (state[S_FLAG]) return;
    unsigned T = state[S_T];
    for (int r = blockIdx.x; r < NWAVES; r += gridDim.x) {
        unsigned cnt = wavecnt[r];
        const uint2* my = cand + (size_t)r * CAPW;
        for (unsigned j = threadIdx.x; j < cnt; j += 256) {
            uint2 e = my[j];
            if ((e.x & 0x7FFFFFFFu) >= T) out[e.y] = __uint_as_float(e.x);
        }
    }
}

// ---------------- fallback chain (round-1 proven exact pipeline, gated) ----------------
__global__ __launch_bounds__(H_THREADS)
void hist_pass1(const uint4* __restrict__ x, long long n4, unsigned* __restrict__ hists,
                const unsigned* __restrict__ state, int gate)
{
    if (gate_skip(state, gate)) return;
    __shared__ unsigned h[NBIN1];
    for (int i = threadIdx.x; i < NBIN1; i += H_THREADS) h[i] = 0u;
    __syncthreads();
    long long stride = (long long)gridDim.x * H_THREADS;
    for (long long i = (long long)blockIdx.x * H_THREADS + threadIdx.x; i < n4; i += stride) {
        uint4 v = x[i];
        atomicAdd(&h[(v.x & 0x7FFFFFFFu) >> 19], 1u);
        atomicAdd(&h[(v.y & 0x7FFFFFFFu) >> 19], 1u);
        atomicAdd(&h[(v.z & 0x7FFFFFFFu) >> 19], 1u);
        atomicAdd(&h[(v.w & 0x7FFFFFFFu) >> 19], 1u);
    }
    __syncthreads();
    unsigned* o = hists + (size_t)blockIdx.x * NBIN1;
    for (int i = threadIdx.x; i < NBIN1; i += H_THREADS) o[i] = h[i];
}

__global__ void hist_reduce(const unsigned* __restrict__ hists, unsigned* __restrict__ histA,
                            int nblocks, const unsigned* __restrict__ state, int gate)
{
    if (gate_skip(state, gate)) return;
    int bin = blockIdx.x * blockDim.x + threadIdx.x;
    if (bin >= NBIN1) return;
    unsigned s = 0;
    for (int b = 0; b < nblocks; ++b) s += hists[(size_t)b * NBIN1 + bin];
    histA[bin] = s;
}

__global__ __launch_bounds__(SEL_T)
void select1_kernel(const unsigned* __restrict__ histA, unsigned* __restrict__ state,
                    unsigned k, int gate)
{
    if (gate_skip(state, gate)) return;
    __shared__ unsigned s_scan[SEL_T];
    __shared__ int s_res[2];
    select_desc(histA, NBIN1, k, s_scan, s_res);
    if (threadIdx.x == 0) {
        state[S_PREF] = (s_res[0] < 0) ? 0u : (unsigned)s_res[0];
        state[S_K1]   = (s_res[0] < 0) ? 1u : (unsigned)s_res[1];
    }
}

__global__ __launch_bounds__(H_THREADS)
void hist_pass2(const uint4* __restrict__ x, long long n4, const unsigned* __restrict__ state,
                unsigned* __restrict__ fineB, unsigned* __restrict__ coarseB, int gate)
{
    if (gate_skip(state, gate)) return;
    __shared__ unsigned hc[NCOARSE];
    for (int i = threadIdx.x; i < NCOARSE; i += H_THREADS) hc[i] = 0u;
    __syncthreads();
    unsigned pref = state[S_PREF];
    long long stride = (long long)gridDim.x * H_THREADS;
    for (long long i = (long long)blockIdx.x * H_THREADS + threadIdx.x; i < n4; i += stride) {
        uint4 v = x[i];
        unsigned u;
#define DO_C(c) u = v.c & 0x7FFFFFFFu;                                        \
        if ((u >> 19) == pref) {                                              \
            atomicAdd(&fineB[u & (NFINE - 1)], 1u);                           \
            atomicAdd(&hc[(u & (NFINE - 1)) >> 10], 1u); }
        DO_C(x) DO_C(y) DO_C(z) DO_C(w)
#undef DO_C
    }
    __syncthreads();
    for (int i = threadIdx.x; i < NCOARSE; i += H_THREADS)
        if (hc[i]) atomicAdd(&coarseB[i], hc[i]);
}

__global__ __launch_bounds__(256)
void mask_kernel(const uint4* __restrict__ x, uint4* __restrict__ out, long long n4,
                 const unsigned* __restrict__ state, int gate)
{
    if (gate_skip(state, gate)) return;
    unsigned t = state[S_T];
    long long stride = (long long)gridDim.x * 256;
    for (long long i = (long long)blockIdx.x * 256 + threadIdx.x; i < n4; i += stride) {
        uint4 v = x[i];
        uint4 r;
        r.x = ((v.x & 0x7FFFFFFFu) >= t) ? v.x : 0u;
        r.y = ((v.y & 0x7FFFFFFFu) >= t) ? v.y : 0u;
        r.z = ((v.z & 0x7FFFFFFFu) >= t) ? v.z : 0u;
        r.w = ((v.w & 0x7FFFFFFFu) >= t) ? v.w : 0u;
        out[i] = r;
    }
}

// ---------------- host ----------------
extern "C" void kernel_launch(void* const* d_in, const int* in_sizes, int n_in,
                              void* d_out, int out_size, void* d_ws, size_t ws_size,
                              hipStream_t stream)
{
    long long n = (long long)in_sizes[0];
    if (n <= 0) return;
    long long n4 = n >> 2;   // n = 4*4096*2048, divisible by 4

    const double FRACTION = 1.0 / 2.718281828459045;   // matches Python 1.0/math.e
    long long k = (long long)((double)n * FRACTION);
    if (k < 1) k = 1;

    // bracket [0.88, 0.92): P(|x|>=.92)=.3576 < k/n=.36788 <= P(|x|>=.88)=.3788
    // (~120 sigma margins for iid N(0,1)); exact on-device verification + fallback
    // covers everything else. Bracket spans coarse bins 2028..2029 only.
    unsigned lo, hi;
    { float f = 0.88f; memcpy(&lo, &f, 4); lo &= 0x7FFFFFFFu; }
    { float f = 0.92f; memcpy(&hi, &f, 4); hi &= 0x7FFFFFFFu; }
    unsigned mid   = hi & ~((1u << 19) - 1);   // floor of hi's coarse bin (0.90625)
    unsigned binhi = mid >> 19;                // 2029

    // buffer layout (relative to bb)
    const size_t off_fineB  = 0;
    const size_t off_coarse = off_fineB  + (size_t)NFINE * 4;
    const size_t off_wcnt   = off_coarse + (size_t)NCOARSE * 4;   // memset up to here
    const size_t off_bchi   = off_wcnt   + (size_t)NWAVES * 4;
    const size_t off_bmid   = off_bchi   + (size_t)P_GRID * 4;
    const size_t off_histA  = off_bmid   + (size_t)P_GRID * 4;
    const size_t off_hists  = off_histA  + (size_t)NBIN1 * 4;
    const size_t off_cand   = off_hists  + (size_t)H_BLOCKS * NBIN1 * 4;
    const size_t cand_bytes = (size_t)NWAVES * CAPW * 8;          // 16 MB
    const size_t need_fast  = 64 + off_cand + cand_bytes;
    const size_t need_ws    = 64 + off_cand;

    unsigned* state = (unsigned*)d_ws;
    uint8_t*  bb;
    bool fast;
    if (ws_size >= need_fast)      { bb = (uint8_t*)d_ws + 64; fast = true;  }
    else if (ws_size >= need_ws)   { bb = (uint8_t*)d_ws + 64; fast = false; }
    else                           { bb = (uint8_t*)d_out;     fast = false; } // staged in d_out

    unsigned* fineB   = (unsigned*)(bb + off_fineB);
    unsigned* coarseB = (unsigned*)(bb + off_coarse);
    unsigned* wavecnt = (unsigned*)(bb + off_wcnt);
    unsigned* blkchi  = (unsigned*)(bb + off_bchi);
    unsigned* blkmid  = (unsigned*)(bb + off_bmid);
    unsigned* histA   = (unsigned*)(bb + off_histA);
    unsigned* hists   = (unsigned*)(bb + off_hists);
    uint2*    cand    = (uint2*)   (bb + off_cand);

    // ws/out are re-poisoned to 0xAA before every timed launch — zero accumulators
    hipMemsetAsync(fineB, 0, ((size_t)NFINE + NCOARSE) * 4, stream);
    hipMemsetAsync(state, 0, 64, stream);

    const uint4* x = (const uint4*)d_in[0];

    if (fast) {
        pass_partition<<<P_GRID, P_BLK, 0, stream>>>(x, n4, lo, hi, mid, (uint4*)d_out,
                                                     cand, wavecnt, blkchi, blkmid, state);
        fast_select   <<<1, 256, 0, stream>>>(blkchi, blkmid, wavecnt, state,
                                              (unsigned)k, binhi);
        cand_hist_fine<<<256, 256, 0, stream>>>(cand, wavecnt, state, fineB, coarseB);
        select2_kernel<<<1, SEL_T, 0, stream>>>(fineB, coarseB, state, 2);
        cand_fixup    <<<256, 256, 0, stream>>>(cand, wavecnt, state, (float*)d_out);
        // gated exact fallback — no-ops unless verification failed
        hist_pass1    <<<H_BLOCKS, H_THREADS, 0, stream>>>(x, n4, hists, state, 1);
        hist_reduce   <<<(NBIN1 + 255) / 256, 256, 0, stream>>>(hists, histA, H_BLOCKS, state, 1);
        select1_kernel<<<1, SEL_T, 0, stream>>>(histA, state, (unsigned)k, 1);
        hist_pass2    <<<H_BLOCKS, H_THREADS, 0, stream>>>(x, n4, state, fineB, coarseB, 1);
        select2_kernel<<<1, SEL_T, 0, stream>>>(fineB, coarseB, state, 1);
        mask_kernel   <<<2048, 256, 0, stream>>>(x, (uint4*)d_out, n4, state, 1);
    } else {
        hist_pass1    <<<H_BLOCKS, H_THREADS, 0, stream>>>(x, n4, hists, state, 0);
        hist_reduce   <<<(NBIN1 + 255) / 256, 256, 0, stream>>>(hists, histA, H_BLOCKS, state, 0);
        select1_kernel<<<1, SEL_T, 0, stream>>>(histA, state, (unsigned)k, 0);
        hist_pass2    <<<H_BLOCKS, H_THREADS, 0, stream>>>(x, n4, state, fineB, coarseB, 0);
        select2_kernel<<<1, SEL_T, 0, stream>>>(fineB, coarseB, state, 0);
        mask_kernel   <<<2048, 256, 0, stream>>>(x, (uint4*)d_out, n4, state, 0);
    }
}

// Round 4
// 307.156 us; speedup vs baseline: 1.2634x; 1.1801x over previous
//
#include <hip/hip_runtime.h>
#include <stdint.h>
#include <string.h>

// BoltzmannGateSTE: out = x * (|x| >= T), T = k-th largest |x|, k = int(n/e).
// Fast path = ONE full read + ONE full write + ~20 MB side traffic:
//   pass_partition: stream x -> out with bracket [LO,HI) = [0.88,0.92):
//     u >= HI -> keep, count chi;  u < LO -> zero;
//     else candidate -> placeholder 0, ballot-compacted append (bits,idx) to a
//     per-wave buffer, and ONE fire-and-forget global atomicAdd into an exact
//     per-bit-pattern count table fineH[u - LO] (671K entries, ~1 hit/bin ->
//     no contention, no LDS, no waitcnt in the hot loop).
//   coarse_reduce: 656-bin coarse sums of fineH (non-atomic).
//   fast_select (1 block): reduce tallies, verify chi < k <= chi+tot, coarse
//     descending scan then fine descending scan -> exact threshold bits.
//   cand_fixup: grid-stride over the candidate arena, write entries >= T.
// Exact gated fallback (proven R1 radix select) covers arbitrary inputs if the
// bracket or a wave buffer ever fails verification (deterministically never for
// this input; margins ~120 sigma). All logic device-side (graph capture).

#define SEL_T 1024

constexpr unsigned LO_BITS = 0x3F6147AEu;        // bits(0.88f)
constexpr unsigned HI_BITS = 0x3F6B851Fu;        // bits(0.92f)
constexpr unsigned NKEY    = HI_BITS - LO_BITS;  // 671089 bracket bit patterns
constexpr int      NCB     = (NKEY + 1023) / 1024;   // 656 coarse bins

constexpr int P_GRID = 4096;                 // partition geometry
constexpr int P_BLK  = 256;
constexpr int P_WPB  = P_BLK / 64;           // 4 waves/block
constexpr int NWAVES = P_GRID * P_WPB;       // 16384
constexpr int CAPW   = 128;                  // slots/wave (mean ~43, 13 sigma)

constexpr int NBIN1   = 4096;                // fallback: bits[30:19]
constexpr int NFINE   = 1 << 19;
constexpr int NCOARSE = 512;
constexpr int F_GRID  = 256;                 // fallback grids (never hot)
constexpr int F_BLK   = 256;

// state slots
#define S_PREF 0
#define S_K1   1
#define S_T    2
#define S_FLAG 3   // nonzero -> fallback chain active

__device__ __forceinline__ bool gate_skip(const unsigned* state, int gate) {
    if (gate == 0) return false;
    unsigned fl = state[S_FLAG];
    return (gate == 1) ? (fl == 0u) : (fl != 0u);
}

// ---------------- fast path ----------------
__global__ __launch_bounds__(P_BLK, 8)
void pass_partition(const uint4* __restrict__ x, long long n4,
                    uint4* __restrict__ out, uint2* __restrict__ cand,
                    unsigned* __restrict__ wavecnt, unsigned* __restrict__ blkchi,
                    unsigned* __restrict__ fineH, unsigned* __restrict__ state)
{
    typedef unsigned uv4 __attribute__((ext_vector_type(4)));
    const int lane  = threadIdx.x & 63;
    const int wid   = threadIdx.x >> 6;
    const int gwave = blockIdx.x * P_WPB + wid;
    uint2* my = cand + (size_t)gwave * CAPW;
    const unsigned long long lt = (1ull << lane) - 1ull;

    unsigned wcnt = 0;          // wave-uniform candidate count
    unsigned chi  = 0;          // per-thread >=HI tally
    const long long stride = (long long)gridDim.x * P_BLK;
#pragma unroll 2
    for (long long i = (long long)blockIdx.x * P_BLK + threadIdx.x; i < n4; i += stride) {
        uint4 v = x[i];
        uint4 r;
        unsigned idx0 = (unsigned)(i << 2);
#define DO_COMP(c, off)                                                        \
        { unsigned b = v.c, u = b & 0x7FFFFFFFu;                               \
          bool kp = (u >= HI_BITS);                                            \
          bool cd = (u >= LO_BITS) & !kp;                                      \
          chi += (unsigned)kp;                                                 \
          r.c = kp ? b : 0u;                                                   \
          unsigned long long m = __ballot(cd);                                 \
          if (cd) {                                                            \
              atomicAdd(&fineH[u - LO_BITS], 1u);  /* fire-and-forget */       \
              unsigned pos = wcnt + (unsigned)__popcll(m & lt);                \
              if (pos < (unsigned)CAPW) my[pos] = make_uint2(b, idx0 + off);   \
          }                                                                    \
          wcnt += (unsigned)__popcll(m); }
        DO_COMP(x, 0) DO_COMP(y, 1) DO_COMP(z, 2) DO_COMP(w, 3)
#undef DO_COMP
        __builtin_nontemporal_store(*(uv4*)&r, (uv4*)(out + i));
    }

    for (int m = 32; m; m >>= 1) chi += __shfl_xor(chi, m, 64);
    __shared__ unsigned s_chi[P_WPB];
    if (lane == 0) {
        s_chi[wid] = chi;
        wavecnt[gwave] = (wcnt < (unsigned)CAPW) ? wcnt : (unsigned)CAPW;
        if (wcnt > (unsigned)CAPW) atomicOr(&state[S_FLAG], 1u);
    }
    __syncthreads();
    if (threadIdx.x == 0) {
        unsigned a = 0;
        for (int w = 0; w < P_WPB; ++w) a += s_chi[w];
        blkchi[blockIdx.x] = a;
    }
}

// 656 blocks x 64: coarseH[b] = sum of fineH[b*1024 .. +1023]
__global__ __launch_bounds__(64)
void coarse_reduce(const unsigned* __restrict__ fineH, unsigned* __restrict__ coarseH)
{
    unsigned base = blockIdx.x << 10;
    unsigned s = 0;
    for (int t = threadIdx.x; t < 1024; t += 64) {
        unsigned key = base + t;
        s += (key < NKEY) ? fineH[key] : 0u;
    }
    for (int m = 32; m; m >>= 1) s += __shfl_xor(s, m, 64);
    if (threadIdx.x == 0) coarseH[blockIdx.x] = s;
}

// ---------------- descending 1-chunk-per-1024 select over a histogram ----------------
__device__ void select_desc(const unsigned* __restrict__ hist, int nbins,
                            unsigned k, unsigned* s_scan, int* s_res)
{
    int tid = threadIdx.x;
    if (tid == 0) { s_res[0] = -1; s_res[1] = 0; }
    __syncthreads();
    unsigned running = 0;
    for (int top = nbins; top > 0; top -= SEL_T) {
        int bin = top - 1 - tid;
        unsigned v = (bin >= 0) ? hist[bin] : 0u;
        s_scan[tid] = v;
        __syncthreads();
        for (int off = 1; off < SEL_T; off <<= 1) {
            unsigned add = (tid >= off) ? s_scan[tid - off] : 0u;
            __syncthreads();
            s_scan[tid] += add;
            __syncthreads();
        }
        unsigned p     = s_scan[tid];
        unsigned pprev = (tid > 0) ? s_scan[tid - 1] : 0u;
        unsigned total = s_scan[SEL_T - 1];
        __syncthreads();
        if (running + total >= k) {
            if (bin >= 0 && running + p >= k && running + pprev < k) {
                s_res[0] = bin;
                s_res[1] = (int)(k - running - pprev);
            }
            __syncthreads();
            return;
        }
        running += total;
    }
    __syncthreads();
}

// 1 block: tally-reduce + verify + coarse scan + fine scan -> exact T
__global__ __launch_bounds__(SEL_T)
void fast_select(const unsigned* __restrict__ blkchi, const unsigned* __restrict__ wavecnt,
                 const unsigned* __restrict__ coarseH, const unsigned* __restrict__ fineH,
                 unsigned* __restrict__ state, unsigned k)
{
    if (state[S_FLAG]) return;   // wave-buffer overflow in partition
    __shared__ unsigned s_scan[SEL_T];
    __shared__ int s_res[2];
    __shared__ unsigned long long s_red[SEL_T / 64][2];
    __shared__ unsigned s_kp;
    __shared__ int s_bad;

    unsigned long long chi = 0, tot = 0;
    for (int i = threadIdx.x; i < P_GRID; i += SEL_T) chi += blkchi[i];
    for (int i = threadIdx.x; i < NWAVES; i += SEL_T) tot += wavecnt[i];
    for (int m = 32; m; m >>= 1) {
        chi += __shfl_xor(chi, m, 64);
        tot += __shfl_xor(tot, m, 64);
    }
    int wid = threadIdx.x >> 6, lane = threadIdx.x & 63;
    if (lane == 0) { s_red[wid][0] = chi; s_red[wid][1] = tot; }
    __syncthreads();
    if (threadIdx.x == 0) {
        unsigned long long C = 0, Tt = 0;
        for (int w = 0; w < SEL_T / 64; ++w) { C += s_red[w][0]; Tt += s_red[w][1]; }
        if (C >= (unsigned long long)k || C + Tt < (unsigned long long)k) {
            state[S_FLAG] = 1u;  // threshold outside bracket -> exact fallback
            s_bad = 1;
        } else { s_bad = 0; s_kp = (unsigned)((unsigned long long)k - C); }
    }
    __syncthreads();
    if (s_bad) return;
    unsigned kp = s_kp;

    select_desc(coarseH, NCB, kp, s_scan, s_res);
    int cb      = s_res[0];
    unsigned r  = (unsigned)s_res[1];
    __syncthreads();
    int nfine = (int)NKEY - cb * 1024;
    if (nfine > 1024) nfine = 1024;
    select_desc(fineH + (size_t)cb * 1024, nfine, r, s_scan, s_res);
    int f = s_res[0];
    if (threadIdx.x == 0)
        state[S_T] = LO_BITS + (unsigned)(cb * 1024 + f);
}

// grid-stride over the whole candidate arena; poison (0x2AAAAAAA) never passes >=T
__global__ __launch_bounds__(256)
void cand_fixup(const uint2* __restrict__ cand, const unsigned* __restrict__ state,
                float* __restrict__ out, long long n)
{
    if (state[S_FLAG]) return;
    unsigned T = state[S_T];
    long long total = (long long)NWAVES * CAPW;
    long long stride = (long long)gridDim.x * 256;
    for (long long j = (long long)blockIdx.x * 256 + threadIdx.x; j < total; j += stride) {
        uint2 e = cand[j];
        if ((e.x & 0x7FFFFFFFu) >= T && e.y < (unsigned long long)n)
            out[e.y] = __uint_as_float(e.x);
    }
}

// ---------------- gated exact fallback (never hot; correctness only) ----------------
__global__ __launch_bounds__(F_BLK)
void f_hist1(const uint4* __restrict__ x, long long n4, unsigned* __restrict__ histA,
             const unsigned* __restrict__ state, int gate)
{
    if (gate_skip(state, gate)) return;
    __shared__ unsigned h[NBIN1];
    for (int i = threadIdx.x; i < NBIN1; i += F_BLK) h[i] = 0u;
    __syncthreads();
    long long stride = (long long)gridDim.x * F_BLK;
    for (long long i = (long long)blockIdx.x * F_BLK + threadIdx.x; i < n4; i += stride) {
        uint4 v = x[i];
        atomicAdd(&h[(v.x & 0x7FFFFFFFu) >> 19], 1u);
        atomicAdd(&h[(v.y & 0x7FFFFFFFu) >> 19], 1u);
        atomicAdd(&h[(v.z & 0x7FFFFFFFu) >> 19], 1u);
        atomicAdd(&h[(v.w & 0x7FFFFFFFu) >> 19], 1u);
    }
    __syncthreads();
    for (int i = threadIdx.x; i < NBIN1; i += F_BLK)
        if (h[i]) atomicAdd(&histA[i], h[i]);
}

__global__ __launch_bounds__(SEL_T)
void f_select1(const unsigned* __restrict__ histA, unsigned* __restrict__ state,
               unsigned k, int gate)
{
    if (gate_skip(state, gate)) return;
    __shared__ unsigned s_scan[SEL_T];
    __shared__ int s_res[2];
    select_desc(histA, NBIN1, k, s_scan, s_res);
    if (threadIdx.x == 0) {
        state[S_PREF] = (s_res[0] < 0) ? 0u : (unsigned)s_res[0];
        state[S_K1]   = (s_res[0] < 0) ? 1u : (unsigned)s_res[1];
    }
}

__global__ __launch_bounds__(F_BLK)
void f_hist2(const uint4* __restrict__ x, long long n4, const unsigned* __restrict__ state,
             unsigned* __restrict__ fineB, unsigned* __restrict__ coarseB, int gate)
{
    if (gate_skip(state, gate)) return;
    __shared__ unsigned hc[NCOARSE];
    for (int i = threadIdx.x; i < NCOARSE; i += F_BLK) hc[i] = 0u;
    __syncthreads();
    unsigned pref = state[S_PREF];
    long long stride = (long long)gridDim.x * F_BLK;
    for (long long i = (long long)blockIdx.x * F_BLK + threadIdx.x; i < n4; i += stride) {
        uint4 v = x[i];
        unsigned u;
#define DO_C(c) u = v.c & 0x7FFFFFFFu;                                        \
        if ((u >> 19) == pref) {                                              \
            atomicAdd(&fineB[u & (NFINE - 1)], 1u);                           \
            atomicAdd(&hc[(u & (NFINE - 1)) >> 10], 1u); }
        DO_C(x) DO_C(y) DO_C(z) DO_C(w)
#undef DO_C
    }
    __syncthreads();
    for (int i = threadIdx.x; i < NCOARSE; i += F_BLK)
        if (hc[i]) atomicAdd(&coarseB[i], hc[i]);
}

__global__ __launch_bounds__(SEL_T)
void f_select2(const unsigned* __restrict__ fineB, const unsigned* __restrict__ coarseB,
               unsigned* __restrict__ state, int gate)
{
    if (gate_skip(state, gate)) return;
    __shared__ unsigned s_scan[SEL_T];
    __shared__ int s_res[2];
    unsigned pref = state[S_PREF];
    unsigned k    = state[S_K1];
    select_desc(coarseB, NCOARSE, k, s_scan, s_res);
    int c       = (s_res[0] < 0) ? 0 : s_res[0];
    unsigned k1 = (s_res[0] < 0) ? 1u : (unsigned)s_res[1];
    __syncthreads();
    select_desc(fineB + (size_t)c * 1024, 1024, k1, s_scan, s_res);
    int f = (s_res[0] < 0) ? 0 : s_res[0];
    if (threadIdx.x == 0)
        state[S_T] = (pref << 19) | ((unsigned)c << 10) | (unsigned)f;
}

__global__ __launch_bounds__(256)
void f_mask(const uint4* __restrict__ x, uint4* __restrict__ out, long long n4,
            const unsigned* __restrict__ state, int gate)
{
    if (gate_skip(state, gate)) return;
    unsigned t = state[S_T];
    long long stride = (long long)gridDim.x * 256;
    for (long long i = (long long)blockIdx.x * 256 + threadIdx.x; i < n4; i += stride) {
        uint4 v = x[i];
        uint4 r;
        r.x = ((v.x & 0x7FFFFFFFu) >= t) ? v.x : 0u;
        r.y = ((v.y & 0x7FFFFFFFu) >= t) ? v.y : 0u;
        r.z = ((v.z & 0x7FFFFFFFu) >= t) ? v.z : 0u;
        r.w = ((v.w & 0x7FFFFFFFu) >= t) ? v.w : 0u;
        out[i] = r;
    }
}

// ---------------- host ----------------
extern "C" void kernel_launch(void* const* d_in, const int* in_sizes, int n_in,
                              void* d_out, int out_size, void* d_ws, size_t ws_size,
                              hipStream_t stream)
{
    long long n = (long long)in_sizes[0];
    if (n <= 0) return;
    long long n4 = n >> 2;   // n = 4*4096*2048, divisible by 4

    const double FRACTION = 1.0 / 2.718281828459045;   // matches Python 1.0/math.e
    long long k = (long long)((double)n * FRACTION);
    if (k < 1) k = 1;

    // contiguous zero region, then non-zeroed buffers
    const size_t off_state   = 0;                                   // 64 B
    const size_t off_fineH   = 64;
    const size_t off_coarseH = off_fineH   + (((size_t)NKEY * 4 + 63) & ~63ull);
    const size_t off_fineB   = off_coarseH + (((size_t)NCB * 4 + 63) & ~63ull);
    const size_t off_coarseB = off_fineB   + (size_t)NFINE * 4;
    const size_t off_histA   = off_coarseB + (size_t)NCOARSE * 4;
    const size_t zero_end    = off_histA   + (size_t)NBIN1 * 4;     // ~4.8 MB
    const size_t off_wcnt    = zero_end;
    const size_t off_bchi    = off_wcnt + (size_t)NWAVES * 4;
    const size_t off_cand    = off_bchi + (size_t)P_GRID * 4;
    const size_t need_fast   = off_cand + (size_t)NWAVES * CAPW * 8;   // ~21.2 MB
    const size_t need_fb     = zero_end;

    uint8_t* base;
    unsigned* state = (unsigned*)d_ws;
    bool fast;
    if (ws_size >= need_fast)     { base = (uint8_t*)d_ws;  fast = true;  }
    else if (ws_size >= need_fb)  { base = (uint8_t*)d_ws;  fast = false; }
    else                          { base = (uint8_t*)d_out; fast = false;   // stage in d_out
                                    state = (unsigned*)d_ws; }

    unsigned* fineH   = (unsigned*)(base + off_fineH);
    unsigned* coarseH = (unsigned*)(base + off_coarseH);
    unsigned* fineB   = (unsigned*)(base + off_fineB);
    unsigned* coarseB = (unsigned*)(base + off_coarseB);
    unsigned* histA   = (unsigned*)(base + off_histA);
    unsigned* wavecnt = (unsigned*)(base + off_wcnt);
    unsigned* blkchi  = (unsigned*)(base + off_bchi);
    uint2*    cand    = (uint2*)   (base + off_cand);

    const uint4* x = (const uint4*)d_in[0];

    if (fast) {
        // single memset: state + fineH + coarseH + fineB + coarseB + histA
        hipMemsetAsync(base, 0, zero_end, stream);
        pass_partition<<<P_GRID, P_BLK, 0, stream>>>(x, n4, (uint4*)d_out, cand,
                                                     wavecnt, blkchi, fineH, state);
        coarse_reduce <<<NCB, 64, 0, stream>>>(fineH, coarseH);
        fast_select   <<<1, SEL_T, 0, stream>>>(blkchi, wavecnt, coarseH, fineH,
                                                state, (unsigned)k);
        cand_fixup    <<<512, 256, 0, stream>>>(cand, state, (float*)d_out, n);
        // gated exact fallback — all no-ops unless verification failed
        f_hist1  <<<F_GRID, F_BLK, 0, stream>>>(x, n4, histA, state, 1);
        f_select1<<<1, SEL_T, 0, stream>>>(histA, state, (unsigned)k, 1);
        f_hist2  <<<F_GRID, F_BLK, 0, stream>>>(x, n4, state, fineB, coarseB, 1);
        f_select2<<<1, SEL_T, 0, stream>>>(fineB, coarseB, state, 1);
        f_mask   <<<1024, 256, 0, stream>>>(x, (uint4*)d_out, n4, state, 1);
    } else {
        if (state == (unsigned*)d_ws && base != (uint8_t*)d_ws)
            hipMemsetAsync(state, 0, 64, stream);
        hipMemsetAsync(base + off_fineB, 0,
                       ((size_t)NFINE + NCOARSE + NBIN1) * 4, stream);
        if (base == (uint8_t*)d_ws) hipMemsetAsync(state, 0, 64, stream);
        f_hist1  <<<F_GRID, F_BLK, 0, stream>>>(x, n4, histA, state, 0);
        f_select1<<<1, SEL_T, 0, stream>>>(histA, state, (unsigned)k, 0);
        f_hist2  <<<F_GRID, F_BLK, 0, stream>>>(x, n4, state, fineB, coarseB, 0);
        f_select2<<<1, SEL_T, 0, stream>>>(fineB, coarseB, state, 0);
        f_mask   <<<1024, 256, 0, stream>>>(x, (uint4*)d_out, n4, state, 0);
    }
}